// Round 11
// baseline (1013.912 us; speedup 1.0000x reference)
//
#include <hip/hip_runtime.h>
#include <hip/hip_bf16.h>
#include <math.h>

#define DEVI __device__ __forceinline__

constexpr int LTOT  = 5376;   // 4096 + 1024 + 256
constexpr int NINST = 100;
constexpr int NCLS  = 80;
constexpr int KPAR  = 169;

DEVI float waveAllSum(float v) {
#pragma unroll
  for (int s = 32; s > 0; s >>= 1) v += __shfl_xor(v, s, 64);
  return v;
}
DEVI float siluf(float x) { return x / (1.0f + expf(-x)); }
DEVI float sigmf(float x) { return 1.0f / (1.0f + expf(-x)); }

// ---------------- transpose lateral weights to k-major (one-time prep) ----------------
__global__ __launch_bounds__(256) void wtrans(
    const float* __restrict__ w3, const float* __restrict__ w4,
    const float* __restrict__ w5, const float* __restrict__ wm,
    float* __restrict__ wt3, float* __restrict__ wt4,
    float* __restrict__ wt5, float* __restrict__ wtm)
{
  __shared__ float t[64][65];
  const int bid = blockIdx.x;
  const float* src; float* dst; int K, rel;
  if (bid < 16)       { src = w3; dst = wt3; K = 256;  rel = bid; }
  else if (bid < 48)  { src = w4; dst = wt4; K = 512;  rel = bid - 16; }
  else if (bid < 112) { src = w5; dst = wt5; K = 1024; rel = bid - 48; }
  else                { src = wm; dst = wtm; K = 256;  rel = bid - 112; }
  const int ctiles = K >> 6;
  const int ot = rel / ctiles, ct = rel % ctiles;
  const int o0 = ot * 64, c0 = ct * 64;
  const int tid = threadIdx.x;
#pragma unroll
  for (int s = 0; s < 16; ++s) {
    const int e = tid + 256*s;
    const int r = e >> 6, c = e & 63;
    t[r][c] = src[(long)(o0 + r)*K + c0 + c];
  }
  __syncthreads();
#pragma unroll
  for (int s = 0; s < 16; ++s) {
    const int e = tid + 256*s;
    const int q = e >> 6, p = e & 63;
    dst[(long)(c0 + q)*256 + o0 + p] = t[p][q];
  }
}

// ---------------- all 1x1 conv + BN laterals (k-major weights, coalesced staging) ----------
__global__ __launch_bounds__(256) void lateral_main(
    const float* __restrict__ x3, const float* __restrict__ x4, const float* __restrict__ x5,
    const float* __restrict__ wt3, const float* __restrict__ s3, const float* __restrict__ b3,
    const float* __restrict__ wt4, const float* __restrict__ s4, const float* __restrict__ b4,
    const float* __restrict__ wt5, const float* __restrict__ s5, const float* __restrict__ b5,
    const float* __restrict__ wtm, const float* __restrict__ sm, const float* __restrict__ bm,
    float* __restrict__ flat, float* __restrict__ mlatb)
{
  __shared__ float xs[32][36];     // [k][px]
  __shared__ float ws[32][256];    // [k][och]
  const int tid = threadIdx.x;
  const int rg = tid >> 6, cg = tid & 63;
  const int bid = blockIdx.x;
  const float *x, *wt, *sc, *bi;
  int K, P, b, p0, baseL = 0; bool tomlat = false;
  if (bid < 512)       { x=x3; wt=wt3; sc=s3; bi=b3; K=256;  P=4096; b=bid>>7;  p0=(bid&127)*32; }
  else if (bid < 1024) { const int rel=bid-512;  x=x3; wt=wtm; sc=sm; bi=bm; K=256;  P=4096; b=rel>>7; p0=(rel&127)*32; tomlat=true; }
  else if (bid < 1152) { const int rel=bid-1024; x=x4; wt=wt4; sc=s4; bi=b4; K=512;  P=1024; b=rel>>5; p0=(rel&31)*32; baseL=4096; }
  else                 { const int rel=bid-1152; x=x5; wt=wt5; sc=s5; bi=b5; K=1024; P=256;  b=rel>>3; p0=(rel&7)*32;  baseL=5120; }
  const float* xb = x + (long)b * K * P;
  float acc[8][4] = {};
  const int nkb = K >> 5;
  for (int kb = 0; kb < nkb; ++kb) {
    __syncthreads();
#pragma unroll
    for (int s = 0; s < 4; ++s) {
      const int e = tid + 256*s;
      const int kk = e >> 5, px = e & 31;
      xs[kk][px] = xb[(long)(kb*32 + kk)*P + p0 + px];
    }
    {
      const float4* w4p = reinterpret_cast<const float4*>(wt + (kb << 13));
#pragma unroll
      for (int q = 0; q < 8; ++q) {
        const int c = tid + (q << 8);
        *reinterpret_cast<float4*>(&ws[c >> 6][4*(c & 63)]) = w4p[c];
      }
    }
    __syncthreads();
#pragma unroll
    for (int kk = 0; kk < 32; ++kk) {
      const float4 a0 = *reinterpret_cast<const float4*>(&xs[kk][8*rg]);
      const float4 a1 = *reinterpret_cast<const float4*>(&xs[kk][8*rg+4]);
      const float ar[8] = {a0.x,a0.y,a0.z,a0.w,a1.x,a1.y,a1.z,a1.w};
      const float4 wv = *reinterpret_cast<const float4*>(&ws[kk][4*cg]);
#pragma unroll
      for (int i = 0; i < 8; ++i) {
        acc[i][0] += ar[i]*wv.x; acc[i][1] += ar[i]*wv.y;
        acc[i][2] += ar[i]*wv.z; acc[i][3] += ar[i]*wv.w;
      }
    }
  }
  const float4 sA = *reinterpret_cast<const float4*>(&sc[4*cg]);
  const float4 bA = *reinterpret_cast<const float4*>(&bi[4*cg]);
  if (!tomlat) {
#pragma unroll
    for (int i = 0; i < 8; ++i) {
      const float4 ov = { acc[i][0]*sA.x+bA.x, acc[i][1]*sA.y+bA.y,
                          acc[i][2]*sA.z+bA.z, acc[i][3]*sA.w+bA.w };
      *reinterpret_cast<float4*>(&flat[((long)b*LTOT + baseL + p0 + 8*rg + i)*256 + 4*cg]) = ov;
    }
  } else {
#pragma unroll
    for (int j = 0; j < 4; ++j) {
      const float sj = (&sA.x)[j], bj = (&bA.x)[j];
      const float4 o0 = { acc[0][j]*sj+bj, acc[1][j]*sj+bj, acc[2][j]*sj+bj, acc[3][j]*sj+bj };
      const float4 o1 = { acc[4][j]*sj+bj, acc[5][j]*sj+bj, acc[6][j]*sj+bj, acc[7][j]*sj+bj };
      float* mb = &mlatb[((long)b*256 + 4*cg + j)*4096 + p0 + 8*rg];
      *reinterpret_cast<float4*>(mb) = o0;
      *reinterpret_cast<float4*>(mb + 4) = o1;
    }
  }
}

// ---------------- loc branch: 4 x (Linear+LN+SiLU) + final 256->1 ----------------
// 768 blocks x 28 rows (4 waves x 7 rows). Wave-local LDS slabs, no barriers.
// 4-deep W (global/L2, ~200cyc) + 2-deep A (LDS broadcast) software pipeline,
// step-4 group loop, all buffers NAMED (static indices only).
__global__ __launch_bounds__(256, 3) void loc4(
    const float* __restrict__ in, const float* __restrict__ hw,
    const float* __restrict__ hb, const float* __restrict__ lng, const float* __restrict__ lnb,
    const float* __restrict__ fw, const float* __restrict__ fb, float* __restrict__ logits)
{
  __shared__ float xls[4][7][256];      // 28 KB, per-wave slabs
  const int tid = threadIdx.x;
  const int rg = tid >> 6, cg = tid & 63;
  const int r0 = blockIdx.x * 28 + rg * 7;
  float* xw = &xls[rg][0][0];
#pragma unroll
  for (int i = 0; i < 7; ++i) {         // stage this wave's rows
    const float4 v = *reinterpret_cast<const float4*>(&in[(long)(r0 + i)*256 + 4*cg]);
    *reinterpret_cast<float4*>(&xw[i*256 + 4*cg]) = v;
  }

#define WL(W, g)                                                            \
  {                                                                         \
    const int kk4 = (g) << 2;                                               \
    W[0] = *reinterpret_cast<const float4*>(&w[(kk4 + 0) << 8]);            \
    W[1] = *reinterpret_cast<const float4*>(&w[(kk4 + 1) << 8]);            \
    W[2] = *reinterpret_cast<const float4*>(&w[(kk4 + 2) << 8]);            \
    W[3] = *reinterpret_cast<const float4*>(&w[(kk4 + 3) << 8]);            \
  }
#define AL(A, g)                                                            \
  {                                                                         \
    const int kk4 = (g) << 2;                                               \
    _Pragma("unroll")                                                       \
    for (int r = 0; r < 7; ++r)                                             \
      A[r] = *reinterpret_cast<const float4*>(&xw[r*256 + kk4]);            \
  }
#define FMAG(W, A)                                                          \
  _Pragma("unroll")                                                         \
  for (int u = 0; u < 4; ++u) {                                             \
    _Pragma("unroll")                                                       \
    for (int r = 0; r < 7; ++r) {                                           \
      const float a = (&A[r].x)[u];                                         \
      acc[r][0] += a*W[u].x; acc[r][1] += a*W[u].y;                         \
      acc[r][2] += a*W[u].z; acc[r][3] += a*W[u].w;                         \
    }                                                                       \
  }
#define MING(a_, b_) ((a_) < (b_) ? (a_) : (b_))

  for (int L = 0; L < 4; ++L) {
    const float* w = hw + L*65536 + 4*cg;
    float acc[7][4] = {};
    float4 w0[4], w1[4], w2[4], w3[4], a0[7], a1[7];
    WL(w0, 0) WL(w1, 1) WL(w2, 2)
    AL(a0, 0) AL(a1, 1)
    for (int g = 0; g < 64; g += 4) {
      WL(w3, MING(g + 3, 63))
      FMAG(w0, a0)                      // group g
      AL(a0, MING(g + 2, 63))
      WL(w0, MING(g + 4, 63))
      FMAG(w1, a1)                      // g+1
      AL(a1, MING(g + 3, 63))
      WL(w1, MING(g + 5, 63))
      FMAG(w2, a0)                      // g+2
      AL(a0, MING(g + 4, 63))
      WL(w2, MING(g + 6, 63))
      FMAG(w3, a1)                      // g+3
      AL(a1, MING(g + 5, 63))
    }
    const float4 hb4 = *reinterpret_cast<const float4*>(&hb[L*256 + 4*cg]);
    const float4 g4  = *reinterpret_cast<const float4*>(&lng[L*256 + 4*cg]);
    const float4 lb4 = *reinterpret_cast<const float4*>(&lnb[L*256 + 4*cg]);
    if (L < 3) {
#pragma unroll
      for (int r = 0; r < 7; ++r) {
        const float y0 = acc[r][0]+hb4.x, y1 = acc[r][1]+hb4.y;
        const float y2 = acc[r][2]+hb4.z, y3 = acc[r][3]+hb4.w;
        const float m = waveAllSum(y0+y1+y2+y3) * (1.0f/256.0f);
        const float d0=y0-m, d1=y1-m, d2=y2-m, d3=y3-m;
        const float var = waveAllSum(d0*d0+d1*d1+d2*d2+d3*d3) * (1.0f/256.0f);
        const float rs = rsqrtf(var + 1e-5f);
        const float4 ov = { siluf(g4.x*d0*rs + lb4.x), siluf(g4.y*d1*rs + lb4.y),
                            siluf(g4.z*d2*rs + lb4.z), siluf(g4.w*d3*rs + lb4.w) };
        *reinterpret_cast<float4*>(&xw[r*256 + 4*cg]) = ov;
      }
    } else {
      const float4 fw4 = *reinterpret_cast<const float4*>(&fw[4*cg]);
      const float fbv = fb[0];
#pragma unroll
      for (int r = 0; r < 7; ++r) {
        const float y0 = acc[r][0]+hb4.x, y1 = acc[r][1]+hb4.y;
        const float y2 = acc[r][2]+hb4.z, y3 = acc[r][3]+hb4.w;
        const float m = waveAllSum(y0+y1+y2+y3) * (1.0f/256.0f);
        const float d0=y0-m, d1=y1-m, d2=y2-m, d3=y3-m;
        const float var = waveAllSum(d0*d0+d1*d1+d2*d2+d3*d3) * (1.0f/256.0f);
        const float rs = rsqrtf(var + 1e-5f);
        const float o0 = siluf(g4.x*d0*rs + lb4.x);
        const float o1 = siluf(g4.y*d1*rs + lb4.y);
        const float o2 = siluf(g4.z*d2*rs + lb4.z);
        const float o3 = siluf(g4.w*d3*rs + lb4.w);
        float d = o0*fw4.x + o1*fw4.y + o2*fw4.z + o3*fw4.w;
        d = waveAllSum(d);
        if (cg == 0) logits[r0 + r] = d + fbv;
      }
    }
  }
#undef WL
#undef AL
#undef FMAG
#undef MING
}

// ---------------- exact stable top-100 + scores + count + gfeat gather ----------------
__global__ __launch_bounds__(256) void topk_gather(
    const float* __restrict__ logits, const float* __restrict__ flat,
    int* __restrict__ topi, float* __restrict__ gfeat,
    float* __restrict__ dout)
{
  __shared__ float sv[LTOT];
  __shared__ float rv[4];
  __shared__ int   ri[4];
  __shared__ int   sidx[NINST];
  const int b = blockIdx.x, tid = threadIdx.x;
  for (int l = tid; l < LTOT; l += 256) sv[l] = logits[b*LTOT + l];
  __syncthreads();
  int cnt = 0;
  for (int t = 0; t < NINST; ++t) {
    float bv = -INFINITY; int bidx = 0x7fffffff;
    for (int l = tid; l < LTOT; l += 256) {
      const float v = sv[l];
      if (v > bv) { bv = v; bidx = l; }
    }
#pragma unroll
    for (int s = 32; s > 0; s >>= 1) {
      const float v2 = __shfl_xor(bv, s, 64);
      const int   i2 = __shfl_xor(bidx, s, 64);
      if (v2 > bv || (v2 == bv && i2 < bidx)) { bv = v2; bidx = i2; }
    }
    if ((tid & 63) == 0) { rv[tid >> 6] = bv; ri[tid >> 6] = bidx; }
    __syncthreads();
    if (tid == 0) {
      bv = rv[0]; bidx = ri[0];
#pragma unroll
      for (int q = 1; q < 4; ++q)
        if (rv[q] > bv || (rv[q] == bv && ri[q] < bidx)) { bv = rv[q]; bidx = ri[q]; }
      sidx[t] = bidx; topi[b*NINST + t] = bidx;
      dout[4 + b*NINST + t] = sigmf(bv);
      if (bv > 0.0f) ++cnt;
      sv[bidx] = -INFINITY;
    }
    __syncthreads();
  }
  if (tid == 0) dout[b] = (float)cnt;
  for (int t = 0; t < NINST; ++t) {
    const int ix = sidx[t];
    gfeat[((long)b*NINST + t)*256 + tid] = flat[((long)b*LTOT + ix)*256 + tid];
  }
}

// ---------------- cls+ker MLPs: 4 fused layers, rows resident in LDS ----------------
__global__ __launch_bounds__(256) void clsker4(
    const float* __restrict__ gfeat, float* __restrict__ h2,
    const float* __restrict__ chw, const float* __restrict__ chb,
    const float* __restrict__ cg_, const float* __restrict__ cb_,
    const float* __restrict__ khw, const float* __restrict__ khb,
    const float* __restrict__ kg_, const float* __restrict__ kb_)
{
  __shared__ float xs[256][12];
  __shared__ float wsm[16][256];
  const int tid = threadIdx.x;
  const int rg = tid >> 6, cg = tid & 63;
  const bool ker = blockIdx.x >= 50;
  const int r0 = (ker ? (blockIdx.x - 50) : blockIdx.x) * 8;
  const int outr0 = r0 + (ker ? 400 : 0);
  const float* hw = ker ? khw : chw;
  const float* hb = ker ? khb : chb;
  const float* g_ = ker ? kg_ : cg_;
  const float* lb = ker ? kb_ : cb_;
#pragma unroll
  for (int s = 0; s < 2; ++s) {
    const int e = tid + 256*s;
    const int row = e >> 6, q = e & 63;
    const float4 v = *reinterpret_cast<const float4*>(&gfeat[(long)(r0 + row)*256 + 4*q]);
    const int pc = 2*((row >> 1) ^ (q & 3)) + (row & 1);
#pragma unroll
    for (int j = 0; j < 4; ++j) xs[4*q+j][pc] = (&v.x)[j];
  }
  float ov[2][4];
  for (int L = 0; L < 4; ++L) {
    const float* w = hw + L*65536;
    float acc[2][4] = {};
    for (int kb = 0; kb < 16; ++kb) {
      __syncthreads();
      const float4* w4 = reinterpret_cast<const float4*>(w + (kb << 12));
#pragma unroll
      for (int q = 0; q < 4; ++q) {
        const int c = tid + (q << 8);
        *reinterpret_cast<float4*>(&wsm[c>>6][4*(c&63)]) = w4[c];
      }
      __syncthreads();
#pragma unroll
      for (int kk = 0; kk < 16; ++kk) {
        const int k = (kb << 4) + kk;
        const float2 av = *reinterpret_cast<const float2*>(&xs[k][2*(rg ^ ((k >> 2) & 3))]);
        const float4 wv = *reinterpret_cast<const float4*>(&wsm[kk][4*cg]);
        acc[0][0] += av.x*wv.x; acc[0][1] += av.x*wv.y; acc[0][2] += av.x*wv.z; acc[0][3] += av.x*wv.w;
        acc[1][0] += av.y*wv.x; acc[1][1] += av.y*wv.y; acc[1][2] += av.y*wv.z; acc[1][3] += av.y*wv.w;
      }
    }
    const float4 hb4 = *reinterpret_cast<const float4*>(&hb[L*256 + 4*cg]);
    const float4 g4  = *reinterpret_cast<const float4*>(&g_[L*256 + 4*cg]);
    const float4 lb4 = *reinterpret_cast<const float4*>(&lb[L*256 + 4*cg]);
#pragma unroll
    for (int i = 0; i < 2; ++i) {
      const float y0 = acc[i][0]+hb4.x, y1 = acc[i][1]+hb4.y;
      const float y2 = acc[i][2]+hb4.z, y3 = acc[i][3]+hb4.w;
      const float m = waveAllSum(y0+y1+y2+y3) * (1.0f/256.0f);
      const float d0=y0-m, d1=y1-m, d2=y2-m, d3=y3-m;
      const float var = waveAllSum(d0*d0+d1*d1+d2*d2+d3*d3) * (1.0f/256.0f);
      const float rs = rsqrtf(var + 1e-5f);
      ov[i][0] = siluf(g4.x*d0*rs + lb4.x);
      ov[i][1] = siluf(g4.y*d1*rs + lb4.y);
      ov[i][2] = siluf(g4.z*d2*rs + lb4.z);
      ov[i][3] = siluf(g4.w*d3*rs + lb4.w);
    }
    __syncthreads();
    if (L < 3) {
      const int pc = 2*(rg ^ (cg & 3));
#pragma unroll
      for (int j = 0; j < 4; ++j) {
        const float2 t = {ov[0][j], ov[1][j]};
        *reinterpret_cast<float2*>(&xs[4*cg+j][pc]) = t;
      }
    }
  }
#pragma unroll
  for (int i = 0; i < 2; ++i) {
    const float4 o = {ov[i][0], ov[i][1], ov[i][2], ov[i][3]};
    *reinterpret_cast<float4*>(&h2[(long)(outr0 + 2*rg + i)*256 + 4*cg]) = o;
  }
}

// ---------------- cls argmax head + ker param head (merged) ----------------
__global__ __launch_bounds__(256) void heads(
    const float* __restrict__ h2, const float* __restrict__ cfw, const float* __restrict__ cfb,
    const float* __restrict__ kfw, const float* __restrict__ kfb,
    float* __restrict__ dout, float* __restrict__ dyn)
{
  __shared__ float xr[256];
  __shared__ float lv[NCLS];
  const int bid = blockIdx.x, tid = threadIdx.x;
  xr[tid] = h2[(long)bid*256 + tid];
  __syncthreads();
  if (bid < 400) {
    if (tid < NCLS) {
      float a0=0.f, a1=0.f, a2=0.f, a3=0.f;
      for (int k = 0; k < 256; k += 4) {
        a0 += xr[k+0]*cfw[(k+0)*NCLS + tid];
        a1 += xr[k+1]*cfw[(k+1)*NCLS + tid];
        a2 += xr[k+2]*cfw[(k+2)*NCLS + tid];
        a3 += xr[k+3]*cfw[(k+3)*NCLS + tid];
      }
      lv[tid] = (a0+a1) + (a2+a3) + cfb[tid];
    }
    __syncthreads();
    if (tid == 0) {
      float bv = lv[0]; int bi2 = 0;
      for (int o = 1; o < NCLS; ++o) if (lv[o] > bv) { bv = lv[o]; bi2 = o; }
      dout[404 + bid] = (float)bi2;
    }
  } else {
    if (tid < KPAR) {
      float a0=0.f, a1=0.f, a2=0.f, a3=0.f;
      for (int k = 0; k < 256; k += 4) {
        a0 += xr[k+0]*kfw[(k+0)*KPAR + tid];
        a1 += xr[k+1]*kfw[(k+1)*KPAR + tid];
        a2 += xr[k+2]*kfw[(k+2)*KPAR + tid];
        a3 += xr[k+3]*kfw[(k+3)*KPAR + tid];
      }
      dyn[(long)(bid-400)*KPAR + tid] = (a0+a1) + (a2+a3) + kfb[tid];
    }
  }
}

// ---------------- 3x3 conv (SAME, zero pad): 32-ch chunks, partials ----------------
__global__ __launch_bounds__(256) void conv3(
    const float* __restrict__ mlat, const float* __restrict__ mw,
    float* __restrict__ partial)
{
  const int bid = blockIdx.x;          // [b(4)][tile(16)][cc(8)]
  const int cc = bid & 7;
  const int tile = (bid >> 3) & 15;
  const int b = bid >> 7;
  const int y0 = (tile >> 2)*16, x0 = (tile & 3)*16;
  const int tid = threadIdx.x;
  const int ly = tid >> 4, lx = tid & 15;
  __shared__ float til[2][18][19];
  __shared__ float wch[8][32][12];
  for (int e = tid; e < 2304; e += 256) {
    const int o = e / 288, rem = e % 288;
    const int c = rem / 9, qq = rem - c*9;
    wch[o][c][qq] = mw[((o*256) + cc*32 + c)*9 + qq];
  }
  int lofs[3], gofs[3], chn[3]; bool vld[3], has[3];
  float* tf = &til[0][0][0];
#pragma unroll
  for (int s = 0; s < 3; ++s) {
    const int e = tid + 256*s;
    has[s] = (e < 648);
    lofs[s] = 0; gofs[s] = 0; chn[s] = 0; vld[s] = false;
    if (has[s]) {
      const int ch = (e >= 324) ? 1 : 0;
      const int pos = e - ch*324;
      const int iy = pos / 18, ix = pos - iy*18;
      const int gy = y0 - 1 + iy, gx = x0 - 1 + ix;
      vld[s] = (gy >= 0 && gy < 64 && gx >= 0 && gx < 64);
      lofs[s] = ch*342 + iy*19 + ix;
      gofs[s] = gy*64 + gx;
      chn[s] = ch;
    }
  }
  const float* xbase = mlat + ((long)b*256 + cc*32)*4096;
  float acc[8] = {};
  for (int r = 0; r < 16; ++r) {
    __syncthreads();
#pragma unroll
    for (int s = 0; s < 3; ++s)
      if (has[s]) tf[lofs[s]] = vld[s] ? xbase[(long)(2*r + chn[s])*4096 + gofs[s]] : 0.f;
    __syncthreads();
#pragma unroll
    for (int ch = 0; ch < 2; ++ch) {
      const int c = 2*r + ch;
      float t[9];
#pragma unroll
      for (int dy = 0; dy < 3; ++dy)
#pragma unroll
        for (int dx = 0; dx < 3; ++dx) t[dy*3+dx] = til[ch][ly+dy][lx+dx];
#pragma unroll
      for (int o = 0; o < 8; ++o) {
        const float4 wa = *reinterpret_cast<const float4*>(&wch[o][c][0]);
        const float4 wb = *reinterpret_cast<const float4*>(&wch[o][c][4]);
        const float w8 = wch[o][c][8];
        acc[o] += t[0]*wa.x + t[1]*wa.y + t[2]*wa.z + t[3]*wa.w
                + t[4]*wb.x + t[5]*wb.y + t[6]*wb.z + t[7]*wb.w + t[8]*w8;
      }
    }
  }
  const long pbase = (((long)b*8 + cc)*8)*4096 + (y0+ly)*64 + (x0+lx);
#pragma unroll
  for (int o = 0; o < 8; ++o) partial[pbase + (long)o*4096] = acc[o];
}

// ---------------- reduce conv partials + affine + SiLU ----------------
__global__ __launch_bounds__(256) void mhead_fin(
    const float* __restrict__ partial, const float* __restrict__ s,
    const float* __restrict__ bi, float* __restrict__ mhead)
{
  const int idx = blockIdx.x*256 + threadIdx.x;
  const int p = idx & 4095;
  const int o = (idx >> 12) & 7;
  const int b = idx >> 15;
  float v = 0.f;
#pragma unroll
  for (int cc = 0; cc < 8; ++cc) v += partial[(((long)b*8 + cc)*8 + o)*4096 + p];
  v = v*s[o] + bi[o];
  mhead[idx] = siluf(v);
}

// ---------------- fused: dynamic 3-layer conv -> sigmoid -> bilinear 8x -> d_out ----------------
__global__ __launch_bounds__(256) void mask_fused(
    const float* __restrict__ dyn, const int* __restrict__ topi,
    const float* __restrict__ mhead, float* __restrict__ dout)
{
  __shared__ float msrc[18][64];
  __shared__ float dd[KPAR];
  __shared__ float so[2];
  const int bid = blockIdx.x;
  const int inst = bid >> 2, q = bid & 3;
  const int tid = threadIdx.x;
  if (tid < KPAR) dd[tid] = dyn[(long)inst*KPAR + tid];
  if (tid == 0) {
    const int l = topi[inst];
    float ox, oy;
    if (l < 4096)      { ox = ((l & 63) + 0.5f)*(1.f/64.f); oy = ((l >> 6) + 0.5f)*(1.f/64.f); }
    else if (l < 5120) { const int t = l - 4096; ox = ((t & 31) + 0.5f)*(1.f/32.f); oy = ((t >> 5) + 0.5f)*(1.f/32.f); }
    else               { const int t = l - 5120; ox = ((t & 15) + 0.5f)*(1.f/16.f); oy = ((t >> 4) + 0.5f)*(1.f/16.f); }
    so[0] = ox; so[1] = oy;
  }
  __syncthreads();
  const float ox = so[0], oy = so[1];
  const int b = inst / NINST;
  const float* mh = mhead + (long)b*8*4096;
  const int r0s = 16*q - 1;
  for (int e = tid; e < 1152; e += 256) {
    const int r = e >> 6, x = e & 63;
    int sy = r0s + r; sy = sy < 0 ? 0 : (sy > 63 ? 63 : sy);
    const int p = sy*64 + x;
    float f[10];
#pragma unroll
    for (int c = 0; c < 8; ++c) f[c] = mh[c*4096 + p];
    f[8] = (x + 0.5f)*(1.f/64.f) - ox;
    f[9] = (sy + 0.5f)*(1.f/64.f) - oy;
    float m1[8];
#pragma unroll
    for (int d = 0; d < 8; ++d) {
      float t = dd[80 + d];
#pragma unroll
      for (int c = 0; c < 10; ++c) t += f[c]*dd[c*8 + d];
      m1[d] = siluf(t);
    }
    float m2[8];
#pragma unroll
    for (int d = 0; d < 8; ++d) {
      float t = dd[152 + d];
#pragma unroll
      for (int c = 0; c < 8; ++c) t += m1[c]*dd[88 + c*8 + d];
      m2[d] = siluf(t);
    }
    float o = dd[168];
#pragma unroll
    for (int c = 0; c < 8; ++c) o += m2[c]*dd[160 + c];
    msrc[r][x] = sigmf(o);
  }
  __syncthreads();
  const int j4 = tid & 127;
  const int half = tid >> 7;
  const int ix0 = (j4 & 1) ? (j4 >> 1) : (j4 >> 1) - 1;
  const int xlo = ix0 < 0 ? 0 : ix0;
  const int xhi = (ix0 + 1 > 63) ? 63 : ix0 + 1;
  float fx[4];
#pragma unroll
  for (int m = 0; m < 4; ++m) {
    const int x = 4*j4 + m;
    const float tx = (x + 0.5f)*0.125f - 0.5f;
    fx[m] = tx - (float)ix0;
  }
  float* dbase = dout + 804 + ((long)inst << 18);
  for (int it = 0; it < 64; ++it) {
    const int yy = 2*it + half;
    const int y = 128*q + yy;
    const float ty = (y + 0.5f)*0.125f - 0.5f;
    const float fyf = floorf(ty);
    const int iy0 = (int)fyf;
    const float fy = ty - fyf;
    const int r0 = iy0 - r0s;
    const float L0 = msrc[r0][xlo],   R0 = msrc[r0][xhi];
    const float L1 = msrc[r0+1][xlo], R1 = msrc[r0+1][xhi];
    const float L = L0 + (L1 - L0)*fy;
    const float R = R0 + (R1 - R0)*fy;
    const float4 ovv = { L + (R - L)*fx[0], L + (R - L)*fx[1],
                         L + (R - L)*fx[2], L + (R - L)*fx[3] };
    *reinterpret_cast<float4*>(&dbase[((long)y << 9) + (j4 << 2)]) = ovv;
  }
}

extern "C" void kernel_launch(void* const* d_in, const int* in_sizes, int n_in,
                              void* d_out, int out_size, void* d_ws, size_t ws_size,
                              hipStream_t stream)
{
  (void)in_sizes; (void)n_in; (void)out_size; (void)ws_size;
  const float* x3      = (const float*)d_in[3];
  const float* x4      = (const float*)d_in[4];
  const float* x5      = (const float*)d_in[5];
  const float* lat3_w  = (const float*)d_in[6];
  const float* lat3_s  = (const float*)d_in[7];
  const float* lat3_b  = (const float*)d_in[8];
  const float* lat4_w  = (const float*)d_in[9];
  const float* lat4_s  = (const float*)d_in[10];
  const float* lat4_b  = (const float*)d_in[11];
  const float* lat5_w  = (const float*)d_in[12];
  const float* lat5_s  = (const float*)d_in[13];
  const float* lat5_b  = (const float*)d_in[14];
  const float* mlat_w  = (const float*)d_in[15];
  const float* mlat_s  = (const float*)d_in[16];
  const float* mlat_b  = (const float*)d_in[17];
  const float* mhead_w = (const float*)d_in[18];
  const float* mhead_s = (const float*)d_in[19];
  const float* mhead_b = (const float*)d_in[20];
  const float* loc_hw  = (const float*)d_in[21];
  const float* loc_hb  = (const float*)d_in[22];
  const float* loc_lng = (const float*)d_in[23];
  const float* loc_lnb = (const float*)d_in[24];
  const float* loc_fw  = (const float*)d_in[25];
  const float* loc_fb  = (const float*)d_in[26];
  const float* cls_hw  = (const float*)d_in[27];
  const float* cls_hb  = (const float*)d_in[28];
  const float* cls_lng = (const float*)d_in[29];
  const float* cls_lnb = (const float*)d_in[30];
  const float* cls_fw  = (const float*)d_in[31];
  const float* cls_fb  = (const float*)d_in[32];
  const float* ker_hw  = (const float*)d_in[33];
  const float* ker_hb  = (const float*)d_in[34];
  const float* ker_lng = (const float*)d_in[35];
  const float* ker_lnb = (const float*)d_in[36];
  const float* ker_fw  = (const float*)d_in[37];
  const float* ker_fb  = (const float*)d_in[38];

  // workspace layout (floats), ~11.8M floats = 47.3 MB
  float* ws      = (float*)d_ws;
  float* flat    = ws;                       // [4][5376][256] = 5,505,024
  float* mlatb   = ws + 5505024;             // [4][256][4096] = 4,194,304
  float* partial = ws + 9699328;             // [4][8][8][4096] = 1,048,576
  float* mheadb  = ws + 10747904;            // [4][8][4096] = 131,072
  float* h2      = ws + 10878976;            // [800][256] = 204,800
  float* logits  = ws + 11083776;            // [4][5376] = 21,504
  int*   topi    = (int*)(ws + 11105280);    // [400]
  float* gfeat   = ws + 11105680;            // [400][256] = 102,400
  float* dynb    = ws + 11208080;            // [400][169] = 67,600
  float* wt3     = ws + 11275680;            // [256][256] = 65,536
  float* wt4     = ws + 11341216;            // [512][256] = 131,072
  float* wt5     = ws + 11472288;            // [1024][256] = 262,144
  float* wtm     = ws + 11734432;            // [256][256] = 65,536
  float* dout    = (float*)d_out;

  wtrans<<<128, 256, 0, stream>>>(lat3_w, lat4_w, lat5_w, mlat_w, wt3, wt4, wt5, wtm);
  lateral_main<<<1184, 256, 0, stream>>>(x3, x4, x5,
      wt3, lat3_s, lat3_b, wt4, lat4_s, lat4_b, wt5, lat5_s, lat5_b,
      wtm, mlat_s, mlat_b, flat, mlatb);
  conv3<<<512, 256, 0, stream>>>(mlatb, mhead_w, partial);
  mhead_fin<<<512, 256, 0, stream>>>(partial, mhead_s, mhead_b, mheadb);
  loc4<<<768, 256, 0, stream>>>(flat, loc_hw, loc_hb, loc_lng, loc_lnb,
                                loc_fw, loc_fb, logits);
  topk_gather<<<4, 256, 0, stream>>>(logits, flat, topi, gfeat, dout);
  clsker4<<<100, 256, 0, stream>>>(gfeat, h2,
      cls_hw, cls_hb, cls_lng, cls_lnb, ker_hw, ker_hb, ker_lng, ker_lnb);
  heads<<<800, 256, 0, stream>>>(h2, cls_fw, cls_fb, ker_fw, ker_fb, dout, dynb);
  mask_fused<<<1600, 256, 0, stream>>>(dynb, topi, mheadb, dout);
}

// Round 12
// 782.559 us; speedup vs baseline: 1.2956x; 1.2956x over previous
//
#include <hip/hip_runtime.h>
#include <hip/hip_bf16.h>
#include <math.h>

#define DEVI __device__ __forceinline__

constexpr int LTOT  = 5376;   // 4096 + 1024 + 256
constexpr int NINST = 100;
constexpr int NCLS  = 80;
constexpr int KPAR  = 169;

DEVI float waveAllSum(float v) {
#pragma unroll
  for (int s = 32; s > 0; s >>= 1) v += __shfl_xor(v, s, 64);
  return v;
}
DEVI float siluf(float x) { return x / (1.0f + expf(-x)); }
DEVI float sigmf(float x) { return 1.0f / (1.0f + expf(-x)); }

// ---------------- transpose lateral weights to k-major (one-time prep) ----------------
__global__ __launch_bounds__(256) void wtrans(
    const float* __restrict__ w3, const float* __restrict__ w4,
    const float* __restrict__ w5, const float* __restrict__ wm,
    float* __restrict__ wt3, float* __restrict__ wt4,
    float* __restrict__ wt5, float* __restrict__ wtm)
{
  __shared__ float t[64][65];
  const int bid = blockIdx.x;
  const float* src; float* dst; int K, rel;
  if (bid < 16)       { src = w3; dst = wt3; K = 256;  rel = bid; }
  else if (bid < 48)  { src = w4; dst = wt4; K = 512;  rel = bid - 16; }
  else if (bid < 112) { src = w5; dst = wt5; K = 1024; rel = bid - 48; }
  else                { src = wm; dst = wtm; K = 256;  rel = bid - 112; }
  const int ctiles = K >> 6;
  const int ot = rel / ctiles, ct = rel % ctiles;
  const int o0 = ot * 64, c0 = ct * 64;
  const int tid = threadIdx.x;
#pragma unroll
  for (int s = 0; s < 16; ++s) {
    const int e = tid + 256*s;
    const int r = e >> 6, c = e & 63;
    t[r][c] = src[(long)(o0 + r)*K + c0 + c];
  }
  __syncthreads();
#pragma unroll
  for (int s = 0; s < 16; ++s) {
    const int e = tid + 256*s;
    const int q = e >> 6, p = e & 63;
    dst[(long)(c0 + q)*256 + o0 + p] = t[p][q];
  }
}

// ---------------- all 1x1 conv + BN laterals (k-major weights, coalesced staging) ----------
__global__ __launch_bounds__(256) void lateral_main(
    const float* __restrict__ x3, const float* __restrict__ x4, const float* __restrict__ x5,
    const float* __restrict__ wt3, const float* __restrict__ s3, const float* __restrict__ b3,
    const float* __restrict__ wt4, const float* __restrict__ s4, const float* __restrict__ b4,
    const float* __restrict__ wt5, const float* __restrict__ s5, const float* __restrict__ b5,
    const float* __restrict__ wtm, const float* __restrict__ sm, const float* __restrict__ bm,
    float* __restrict__ flat, float* __restrict__ mlatb)
{
  __shared__ float xs[32][36];     // [k][px]
  __shared__ float ws[32][256];    // [k][och]
  const int tid = threadIdx.x;
  const int rg = tid >> 6, cg = tid & 63;
  const int bid = blockIdx.x;
  const float *x, *wt, *sc, *bi;
  int K, P, b, p0, baseL = 0; bool tomlat = false;
  if (bid < 512)       { x=x3; wt=wt3; sc=s3; bi=b3; K=256;  P=4096; b=bid>>7;  p0=(bid&127)*32; }
  else if (bid < 1024) { const int rel=bid-512;  x=x3; wt=wtm; sc=sm; bi=bm; K=256;  P=4096; b=rel>>7; p0=(rel&127)*32; tomlat=true; }
  else if (bid < 1152) { const int rel=bid-1024; x=x4; wt=wt4; sc=s4; bi=b4; K=512;  P=1024; b=rel>>5; p0=(rel&31)*32; baseL=4096; }
  else                 { const int rel=bid-1152; x=x5; wt=wt5; sc=s5; bi=b5; K=1024; P=256;  b=rel>>3; p0=(rel&7)*32;  baseL=5120; }
  const float* xb = x + (long)b * K * P;
  float acc[8][4] = {};
  const int nkb = K >> 5;
  for (int kb = 0; kb < nkb; ++kb) {
    __syncthreads();
#pragma unroll
    for (int s = 0; s < 4; ++s) {
      const int e = tid + 256*s;
      const int kk = e >> 5, px = e & 31;
      xs[kk][px] = xb[(long)(kb*32 + kk)*P + p0 + px];
    }
    {
      const float4* w4p = reinterpret_cast<const float4*>(wt + (kb << 13));
#pragma unroll
      for (int q = 0; q < 8; ++q) {
        const int c = tid + (q << 8);
        *reinterpret_cast<float4*>(&ws[c >> 6][4*(c & 63)]) = w4p[c];
      }
    }
    __syncthreads();
#pragma unroll
    for (int kk = 0; kk < 32; ++kk) {
      const float4 a0 = *reinterpret_cast<const float4*>(&xs[kk][8*rg]);
      const float4 a1 = *reinterpret_cast<const float4*>(&xs[kk][8*rg+4]);
      const float ar[8] = {a0.x,a0.y,a0.z,a0.w,a1.x,a1.y,a1.z,a1.w};
      const float4 wv = *reinterpret_cast<const float4*>(&ws[kk][4*cg]);
#pragma unroll
      for (int i = 0; i < 8; ++i) {
        acc[i][0] += ar[i]*wv.x; acc[i][1] += ar[i]*wv.y;
        acc[i][2] += ar[i]*wv.z; acc[i][3] += ar[i]*wv.w;
      }
    }
  }
  const float4 sA = *reinterpret_cast<const float4*>(&sc[4*cg]);
  const float4 bA = *reinterpret_cast<const float4*>(&bi[4*cg]);
  if (!tomlat) {
#pragma unroll
    for (int i = 0; i < 8; ++i) {
      const float4 ov = { acc[i][0]*sA.x+bA.x, acc[i][1]*sA.y+bA.y,
                          acc[i][2]*sA.z+bA.z, acc[i][3]*sA.w+bA.w };
      *reinterpret_cast<float4*>(&flat[((long)b*LTOT + baseL + p0 + 8*rg + i)*256 + 4*cg]) = ov;
    }
  } else {
#pragma unroll
    for (int j = 0; j < 4; ++j) {
      const float sj = (&sA.x)[j], bj = (&bA.x)[j];
      const float4 o0 = { acc[0][j]*sj+bj, acc[1][j]*sj+bj, acc[2][j]*sj+bj, acc[3][j]*sj+bj };
      const float4 o1 = { acc[4][j]*sj+bj, acc[5][j]*sj+bj, acc[6][j]*sj+bj, acc[7][j]*sj+bj };
      float* mb = &mlatb[((long)b*256 + 4*cg + j)*4096 + p0 + 8*rg];
      *reinterpret_cast<float4*>(mb) = o0;
      *reinterpret_cast<float4*>(mb + 4) = o1;
    }
  }
}

// ---------------- loc branch: 4 x (Linear+LN+SiLU) + final 256->1 ----------------
// 768 blocks x 28 rows (4 waves x 7 rows). Wave-local LDS slabs, no barriers.
// 2-deep software pipeline over 4-k groups with NAMED A/B register sets.
// amdgpu_waves_per_eu(3,3): max occupancy pinned to 3 waves/EU so the register
// allocator may use ~170 VGPRs and keep the prefetch buffers live (no sinking).
__global__ __attribute__((amdgpu_waves_per_eu(3, 3))) __launch_bounds__(256)
void loc4(
    const float* __restrict__ in, const float* __restrict__ hw,
    const float* __restrict__ hb, const float* __restrict__ lng, const float* __restrict__ lnb,
    const float* __restrict__ fw, const float* __restrict__ fb, float* __restrict__ logits)
{
  __shared__ float xls[4][7][256];      // 28 KB, per-wave slabs
  const int tid = threadIdx.x;
  const int rg = tid >> 6, cg = tid & 63;
  const int r0 = blockIdx.x * 28 + rg * 7;
  float* xw = &xls[rg][0][0];
#pragma unroll
  for (int i = 0; i < 7; ++i) {         // stage this wave's rows
    const float4 v = *reinterpret_cast<const float4*>(&in[(long)(r0 + i)*256 + 4*cg]);
    *reinterpret_cast<float4*>(&xw[i*256 + 4*cg]) = v;
  }
  const float4 fw4 = *reinterpret_cast<const float4*>(&fw[4*cg]);
  const float fbv = fb[0];

#define LOADG(W, A, g)                                                      \
  {                                                                         \
    const int kk4 = (g) << 2;                                               \
    W[0] = *reinterpret_cast<const float4*>(&w[(kk4 + 0) << 8]);            \
    W[1] = *reinterpret_cast<const float4*>(&w[(kk4 + 1) << 8]);            \
    W[2] = *reinterpret_cast<const float4*>(&w[(kk4 + 2) << 8]);            \
    W[3] = *reinterpret_cast<const float4*>(&w[(kk4 + 3) << 8]);            \
    _Pragma("unroll")                                                       \
    for (int r = 0; r < 7; ++r)                                             \
      A[r] = *reinterpret_cast<const float4*>(&xw[r*256 + kk4]);            \
  }
#define FMAG(W, A)                                                          \
  _Pragma("unroll")                                                         \
  for (int u = 0; u < 4; ++u) {                                             \
    _Pragma("unroll")                                                       \
    for (int r = 0; r < 7; ++r) {                                           \
      const float a = (&A[r].x)[u];                                         \
      acc[r][0] += a*W[u].x; acc[r][1] += a*W[u].y;                         \
      acc[r][2] += a*W[u].z; acc[r][3] += a*W[u].w;                         \
    }                                                                       \
  }

  for (int L = 0; L < 4; ++L) {
    const float* w = hw + L*65536 + 4*cg;
    float acc[7][4] = {};
    float4 wvA[4], wvB[4], avA[7], avB[7];
    LOADG(wvA, avA, 0)                    // prologue: group 0 -> A
    for (int g = 0; g < 64; g += 2) {
      LOADG(wvB, avB, g + 1)              // prefetch g+1 -> B
      FMAG(wvA, avA)                      // compute g
      if (g + 2 < 64) LOADG(wvA, avA, g + 2)   // prefetch g+2 -> A
      FMAG(wvB, avB)                      // compute g+1
    }
    const float4 hb4 = *reinterpret_cast<const float4*>(&hb[L*256 + 4*cg]);
    const float4 g4  = *reinterpret_cast<const float4*>(&lng[L*256 + 4*cg]);
    const float4 lb4 = *reinterpret_cast<const float4*>(&lnb[L*256 + 4*cg]);
#pragma unroll
    for (int r = 0; r < 7; ++r) {
      const float y0 = acc[r][0]+hb4.x, y1 = acc[r][1]+hb4.y;
      const float y2 = acc[r][2]+hb4.z, y3 = acc[r][3]+hb4.w;
      const float m = waveAllSum(y0+y1+y2+y3) * (1.0f/256.0f);
      const float d0=y0-m, d1=y1-m, d2=y2-m, d3=y3-m;
      const float var = waveAllSum(d0*d0+d1*d1+d2*d2+d3*d3) * (1.0f/256.0f);
      const float rs = rsqrtf(var + 1e-5f);
      const float o0 = siluf(g4.x*d0*rs + lb4.x);
      const float o1 = siluf(g4.y*d1*rs + lb4.y);
      const float o2 = siluf(g4.z*d2*rs + lb4.z);
      const float o3 = siluf(g4.w*d3*rs + lb4.w);
      if (L < 3) {
        const float4 ov = {o0, o1, o2, o3};
        *reinterpret_cast<float4*>(&xw[r*256 + 4*cg]) = ov;
      } else {
        float d = o0*fw4.x + o1*fw4.y + o2*fw4.z + o3*fw4.w;
        d = waveAllSum(d);
        if (cg == 0) logits[r0 + r] = d + fbv;
      }
    }
  }
#undef LOADG
#undef FMAG
}

// ---------------- exact stable top-100 + scores + count + gfeat gather ----------------
__global__ __launch_bounds__(256) void topk_gather(
    const float* __restrict__ logits, const float* __restrict__ flat,
    int* __restrict__ topi, float* __restrict__ gfeat,
    float* __restrict__ dout)
{
  __shared__ float sv[LTOT];
  __shared__ float rv[4];
  __shared__ int   ri[4];
  __shared__ int   sidx[NINST];
  const int b = blockIdx.x, tid = threadIdx.x;
  for (int l = tid; l < LTOT; l += 256) sv[l] = logits[b*LTOT + l];
  __syncthreads();
  int cnt = 0;
  for (int t = 0; t < NINST; ++t) {
    float bv = -INFINITY; int bidx = 0x7fffffff;
    for (int l = tid; l < LTOT; l += 256) {
      const float v = sv[l];
      if (v > bv) { bv = v; bidx = l; }
    }
#pragma unroll
    for (int s = 32; s > 0; s >>= 1) {
      const float v2 = __shfl_xor(bv, s, 64);
      const int   i2 = __shfl_xor(bidx, s, 64);
      if (v2 > bv || (v2 == bv && i2 < bidx)) { bv = v2; bidx = i2; }
    }
    if ((tid & 63) == 0) { rv[tid >> 6] = bv; ri[tid >> 6] = bidx; }
    __syncthreads();
    if (tid == 0) {
      bv = rv[0]; bidx = ri[0];
#pragma unroll
      for (int q = 1; q < 4; ++q)
        if (rv[q] > bv || (rv[q] == bv && ri[q] < bidx)) { bv = rv[q]; bidx = ri[q]; }
      sidx[t] = bidx; topi[b*NINST + t] = bidx;
      dout[4 + b*NINST + t] = sigmf(bv);
      if (bv > 0.0f) ++cnt;
      sv[bidx] = -INFINITY;
    }
    __syncthreads();
  }
  if (tid == 0) dout[b] = (float)cnt;
  for (int t = 0; t < NINST; ++t) {
    const int ix = sidx[t];
    gfeat[((long)b*NINST + t)*256 + tid] = flat[((long)b*LTOT + ix)*256 + tid];
  }
}

// ---------------- cls+ker MLPs: 4 fused layers, rows resident in LDS ----------------
__global__ __launch_bounds__(256) void clsker4(
    const float* __restrict__ gfeat, float* __restrict__ h2,
    const float* __restrict__ chw, const float* __restrict__ chb,
    const float* __restrict__ cg_, const float* __restrict__ cb_,
    const float* __restrict__ khw, const float* __restrict__ khb,
    const float* __restrict__ kg_, const float* __restrict__ kb_)
{
  __shared__ float xs[256][12];
  __shared__ float wsm[16][256];
  const int tid = threadIdx.x;
  const int rg = tid >> 6, cg = tid & 63;
  const bool ker = blockIdx.x >= 50;
  const int r0 = (ker ? (blockIdx.x - 50) : blockIdx.x) * 8;
  const int outr0 = r0 + (ker ? 400 : 0);
  const float* hw = ker ? khw : chw;
  const float* hb = ker ? khb : chb;
  const float* g_ = ker ? kg_ : cg_;
  const float* lb = ker ? kb_ : cb_;
#pragma unroll
  for (int s = 0; s < 2; ++s) {
    const int e = tid + 256*s;
    const int row = e >> 6, q = e & 63;
    const float4 v = *reinterpret_cast<const float4*>(&gfeat[(long)(r0 + row)*256 + 4*q]);
    const int pc = 2*((row >> 1) ^ (q & 3)) + (row & 1);
#pragma unroll
    for (int j = 0; j < 4; ++j) xs[4*q+j][pc] = (&v.x)[j];
  }
  float ov[2][4];
  for (int L = 0; L < 4; ++L) {
    const float* w = hw + L*65536;
    float acc[2][4] = {};
    for (int kb = 0; kb < 16; ++kb) {
      __syncthreads();
      const float4* w4 = reinterpret_cast<const float4*>(w + (kb << 12));
#pragma unroll
      for (int q = 0; q < 4; ++q) {
        const int c = tid + (q << 8);
        *reinterpret_cast<float4*>(&wsm[c>>6][4*(c&63)]) = w4[c];
      }
      __syncthreads();
#pragma unroll
      for (int kk = 0; kk < 16; ++kk) {
        const int k = (kb << 4) + kk;
        const float2 av = *reinterpret_cast<const float2*>(&xs[k][2*(rg ^ ((k >> 2) & 3))]);
        const float4 wv = *reinterpret_cast<const float4*>(&wsm[kk][4*cg]);
        acc[0][0] += av.x*wv.x; acc[0][1] += av.x*wv.y; acc[0][2] += av.x*wv.z; acc[0][3] += av.x*wv.w;
        acc[1][0] += av.y*wv.x; acc[1][1] += av.y*wv.y; acc[1][2] += av.y*wv.z; acc[1][3] += av.y*wv.w;
      }
    }
    const float4 hb4 = *reinterpret_cast<const float4*>(&hb[L*256 + 4*cg]);
    const float4 g4  = *reinterpret_cast<const float4*>(&g_[L*256 + 4*cg]);
    const float4 lb4 = *reinterpret_cast<const float4*>(&lb[L*256 + 4*cg]);
#pragma unroll
    for (int i = 0; i < 2; ++i) {
      const float y0 = acc[i][0]+hb4.x, y1 = acc[i][1]+hb4.y;
      const float y2 = acc[i][2]+hb4.z, y3 = acc[i][3]+hb4.w;
      const float m = waveAllSum(y0+y1+y2+y3) * (1.0f/256.0f);
      const float d0=y0-m, d1=y1-m, d2=y2-m, d3=y3-m;
      const float var = waveAllSum(d0*d0+d1*d1+d2*d2+d3*d3) * (1.0f/256.0f);
      const float rs = rsqrtf(var + 1e-5f);
      ov[i][0] = siluf(g4.x*d0*rs + lb4.x);
      ov[i][1] = siluf(g4.y*d1*rs + lb4.y);
      ov[i][2] = siluf(g4.z*d2*rs + lb4.z);
      ov[i][3] = siluf(g4.w*d3*rs + lb4.w);
    }
    __syncthreads();
    if (L < 3) {
      const int pc = 2*(rg ^ (cg & 3));
#pragma unroll
      for (int j = 0; j < 4; ++j) {
        const float2 t = {ov[0][j], ov[1][j]};
        *reinterpret_cast<float2*>(&xs[4*cg+j][pc]) = t;
      }
    }
  }
#pragma unroll
  for (int i = 0; i < 2; ++i) {
    const float4 o = {ov[i][0], ov[i][1], ov[i][2], ov[i][3]};
    *reinterpret_cast<float4*>(&h2[(long)(outr0 + 2*rg + i)*256 + 4*cg]) = o;
  }
}

// ---------------- cls argmax head + ker param head (merged) ----------------
__global__ __launch_bounds__(256) void heads(
    const float* __restrict__ h2, const float* __restrict__ cfw, const float* __restrict__ cfb,
    const float* __restrict__ kfw, const float* __restrict__ kfb,
    float* __restrict__ dout, float* __restrict__ dyn)
{
  __shared__ float xr[256];
  __shared__ float lv[NCLS];
  const int bid = blockIdx.x, tid = threadIdx.x;
  xr[tid] = h2[(long)bid*256 + tid];
  __syncthreads();
  if (bid < 400) {
    if (tid < NCLS) {
      float a0=0.f, a1=0.f, a2=0.f, a3=0.f;
      for (int k = 0; k < 256; k += 4) {
        a0 += xr[k+0]*cfw[(k+0)*NCLS + tid];
        a1 += xr[k+1]*cfw[(k+1)*NCLS + tid];
        a2 += xr[k+2]*cfw[(k+2)*NCLS + tid];
        a3 += xr[k+3]*cfw[(k+3)*NCLS + tid];
      }
      lv[tid] = (a0+a1) + (a2+a3) + cfb[tid];
    }
    __syncthreads();
    if (tid == 0) {
      float bv = lv[0]; int bi2 = 0;
      for (int o = 1; o < NCLS; ++o) if (lv[o] > bv) { bv = lv[o]; bi2 = o; }
      dout[404 + bid] = (float)bi2;
    }
  } else {
    if (tid < KPAR) {
      float a0=0.f, a1=0.f, a2=0.f, a3=0.f;
      for (int k = 0; k < 256; k += 4) {
        a0 += xr[k+0]*kfw[(k+0)*KPAR + tid];
        a1 += xr[k+1]*kfw[(k+1)*KPAR + tid];
        a2 += xr[k+2]*kfw[(k+2)*KPAR + tid];
        a3 += xr[k+3]*kfw[(k+3)*KPAR + tid];
      }
      dyn[(long)(bid-400)*KPAR + tid] = (a0+a1) + (a2+a3) + kfb[tid];
    }
  }
}

// ---------------- 3x3 conv (SAME, zero pad): 32-ch chunks, partials ----------------
__global__ __launch_bounds__(256) void conv3(
    const float* __restrict__ mlat, const float* __restrict__ mw,
    float* __restrict__ partial)
{
  const int bid = blockIdx.x;          // [b(4)][tile(16)][cc(8)]
  const int cc = bid & 7;
  const int tile = (bid >> 3) & 15;
  const int b = bid >> 7;
  const int y0 = (tile >> 2)*16, x0 = (tile & 3)*16;
  const int tid = threadIdx.x;
  const int ly = tid >> 4, lx = tid & 15;
  __shared__ float til[2][18][19];
  __shared__ float wch[8][32][12];
  for (int e = tid; e < 2304; e += 256) {
    const int o = e / 288, rem = e % 288;
    const int c = rem / 9, qq = rem - c*9;
    wch[o][c][qq] = mw[((o*256) + cc*32 + c)*9 + qq];
  }
  int lofs[3], gofs[3], chn[3]; bool vld[3], has[3];
  float* tf = &til[0][0][0];
#pragma unroll
  for (int s = 0; s < 3; ++s) {
    const int e = tid + 256*s;
    has[s] = (e < 648);
    lofs[s] = 0; gofs[s] = 0; chn[s] = 0; vld[s] = false;
    if (has[s]) {
      const int ch = (e >= 324) ? 1 : 0;
      const int pos = e - ch*324;
      const int iy = pos / 18, ix = pos - iy*18;
      const int gy = y0 - 1 + iy, gx = x0 - 1 + ix;
      vld[s] = (gy >= 0 && gy < 64 && gx >= 0 && gx < 64);
      lofs[s] = ch*342 + iy*19 + ix;
      gofs[s] = gy*64 + gx;
      chn[s] = ch;
    }
  }
  const float* xbase = mlat + ((long)b*256 + cc*32)*4096;
  float acc[8] = {};
  for (int r = 0; r < 16; ++r) {
    __syncthreads();
#pragma unroll
    for (int s = 0; s < 3; ++s)
      if (has[s]) tf[lofs[s]] = vld[s] ? xbase[(long)(2*r + chn[s])*4096 + gofs[s]] : 0.f;
    __syncthreads();
#pragma unroll
    for (int ch = 0; ch < 2; ++ch) {
      const int c = 2*r + ch;
      float t[9];
#pragma unroll
      for (int dy = 0; dy < 3; ++dy)
#pragma unroll
        for (int dx = 0; dx < 3; ++dx) t[dy*3+dx] = til[ch][ly+dy][lx+dx];
#pragma unroll
      for (int o = 0; o < 8; ++o) {
        const float4 wa = *reinterpret_cast<const float4*>(&wch[o][c][0]);
        const float4 wb = *reinterpret_cast<const float4*>(&wch[o][c][4]);
        const float w8 = wch[o][c][8];
        acc[o] += t[0]*wa.x + t[1]*wa.y + t[2]*wa.z + t[3]*wa.w
                + t[4]*wb.x + t[5]*wb.y + t[6]*wb.z + t[7]*wb.w + t[8]*w8;
      }
    }
  }
  const long pbase = (((long)b*8 + cc)*8)*4096 + (y0+ly)*64 + (x0+lx);
#pragma unroll
  for (int o = 0; o < 8; ++o) partial[pbase + (long)o*4096] = acc[o];
}

// ---------------- reduce conv partials + affine + SiLU ----------------
__global__ __launch_bounds__(256) void mhead_fin(
    const float* __restrict__ partial, const float* __restrict__ s,
    const float* __restrict__ bi, float* __restrict__ mhead)
{
  const int idx = blockIdx.x*256 + threadIdx.x;
  const int p = idx & 4095;
  const int o = (idx >> 12) & 7;
  const int b = idx >> 15;
  float v = 0.f;
#pragma unroll
  for (int cc = 0; cc < 8; ++cc) v += partial[(((long)b*8 + cc)*8 + o)*4096 + p];
  v = v*s[o] + bi[o];
  mhead[idx] = siluf(v);
}

// ---------------- fused: dynamic 3-layer conv -> sigmoid -> bilinear 8x -> d_out ----------------
__global__ __launch_bounds__(256) void mask_fused(
    const float* __restrict__ dyn, const int* __restrict__ topi,
    const float* __restrict__ mhead, float* __restrict__ dout)
{
  __shared__ float msrc[18][64];
  __shared__ float dd[KPAR];
  __shared__ float so[2];
  const int bid = blockIdx.x;
  const int inst = bid >> 2, q = bid & 3;
  const int tid = threadIdx.x;
  if (tid < KPAR) dd[tid] = dyn[(long)inst*KPAR + tid];
  if (tid == 0) {
    const int l = topi[inst];
    float ox, oy;
    if (l < 4096)      { ox = ((l & 63) + 0.5f)*(1.f/64.f); oy = ((l >> 6) + 0.5f)*(1.f/64.f); }
    else if (l < 5120) { const int t = l - 4096; ox = ((t & 31) + 0.5f)*(1.f/32.f); oy = ((t >> 5) + 0.5f)*(1.f/32.f); }
    else               { const int t = l - 5120; ox = ((t & 15) + 0.5f)*(1.f/16.f); oy = ((t >> 4) + 0.5f)*(1.f/16.f); }
    so[0] = ox; so[1] = oy;
  }
  __syncthreads();
  const float ox = so[0], oy = so[1];
  const int b = inst / NINST;
  const float* mh = mhead + (long)b*8*4096;
  const int r0s = 16*q - 1;
  for (int e = tid; e < 1152; e += 256) {
    const int r = e >> 6, x = e & 63;
    int sy = r0s + r; sy = sy < 0 ? 0 : (sy > 63 ? 63 : sy);
    const int p = sy*64 + x;
    float f[10];
#pragma unroll
    for (int c = 0; c < 8; ++c) f[c] = mh[c*4096 + p];
    f[8] = (x + 0.5f)*(1.f/64.f) - ox;
    f[9] = (sy + 0.5f)*(1.f/64.f) - oy;
    float m1[8];
#pragma unroll
    for (int d = 0; d < 8; ++d) {
      float t = dd[80 + d];
#pragma unroll
      for (int c = 0; c < 10; ++c) t += f[c]*dd[c*8 + d];
      m1[d] = siluf(t);
    }
    float m2[8];
#pragma unroll
    for (int d = 0; d < 8; ++d) {
      float t = dd[152 + d];
#pragma unroll
      for (int c = 0; c < 8; ++c) t += m1[c]*dd[88 + c*8 + d];
      m2[d] = siluf(t);
    }
    float o = dd[168];
#pragma unroll
    for (int c = 0; c < 8; ++c) o += m2[c]*dd[160 + c];
    msrc[r][x] = sigmf(o);
  }
  __syncthreads();
  const int j4 = tid & 127;
  const int half = tid >> 7;
  const int ix0 = (j4 & 1) ? (j4 >> 1) : (j4 >> 1) - 1;
  const int xlo = ix0 < 0 ? 0 : ix0;
  const int xhi = (ix0 + 1 > 63) ? 63 : ix0 + 1;
  float fx[4];
#pragma unroll
  for (int m = 0; m < 4; ++m) {
    const int x = 4*j4 + m;
    const float tx = (x + 0.5f)*0.125f - 0.5f;
    fx[m] = tx - (float)ix0;
  }
  float* dbase = dout + 804 + ((long)inst << 18);
  for (int it = 0; it < 64; ++it) {
    const int yy = 2*it + half;
    const int y = 128*q + yy;
    const float ty = (y + 0.5f)*0.125f - 0.5f;
    const float fyf = floorf(ty);
    const int iy0 = (int)fyf;
    const float fy = ty - fyf;
    const int r0 = iy0 - r0s;
    const float L0 = msrc[r0][xlo],   R0 = msrc[r0][xhi];
    const float L1 = msrc[r0+1][xlo], R1 = msrc[r0+1][xhi];
    const float L = L0 + (L1 - L0)*fy;
    const float R = R0 + (R1 - R0)*fy;
    const float4 ovv = { L + (R - L)*fx[0], L + (R - L)*fx[1],
                         L + (R - L)*fx[2], L + (R - L)*fx[3] };
    *reinterpret_cast<float4*>(&dbase[((long)y << 9) + (j4 << 2)]) = ovv;
  }
}

extern "C" void kernel_launch(void* const* d_in, const int* in_sizes, int n_in,
                              void* d_out, int out_size, void* d_ws, size_t ws_size,
                              hipStream_t stream)
{
  (void)in_sizes; (void)n_in; (void)out_size; (void)ws_size;
  const float* x3      = (const float*)d_in[3];
  const float* x4      = (const float*)d_in[4];
  const float* x5      = (const float*)d_in[5];
  const float* lat3_w  = (const float*)d_in[6];
  const float* lat3_s  = (const float*)d_in[7];
  const float* lat3_b  = (const float*)d_in[8];
  const float* lat4_w  = (const float*)d_in[9];
  const float* lat4_s  = (const float*)d_in[10];
  const float* lat4_b  = (const float*)d_in[11];
  const float* lat5_w  = (const float*)d_in[12];
  const float* lat5_s  = (const float*)d_in[13];
  const float* lat5_b  = (const float*)d_in[14];
  const float* mlat_w  = (const float*)d_in[15];
  const float* mlat_s  = (const float*)d_in[16];
  const float* mlat_b  = (const float*)d_in[17];
  const float* mhead_w = (const float*)d_in[18];
  const float* mhead_s = (const float*)d_in[19];
  const float* mhead_b = (const float*)d_in[20];
  const float* loc_hw  = (const float*)d_in[21];
  const float* loc_hb  = (const float*)d_in[22];
  const float* loc_lng = (const float*)d_in[23];
  const float* loc_lnb = (const float*)d_in[24];
  const float* loc_fw  = (const float*)d_in[25];
  const float* loc_fb  = (const float*)d_in[26];
  const float* cls_hw  = (const float*)d_in[27];
  const float* cls_hb  = (const float*)d_in[28];
  const float* cls_lng = (const float*)d_in[29];
  const float* cls_lnb = (const float*)d_in[30];
  const float* cls_fw  = (const float*)d_in[31];
  const float* cls_fb  = (const float*)d_in[32];
  const float* ker_hw  = (const float*)d_in[33];
  const float* ker_hb  = (const float*)d_in[34];
  const float* ker_lng = (const float*)d_in[35];
  const float* ker_lnb = (const float*)d_in[36];
  const float* ker_fw  = (const float*)d_in[37];
  const float* ker_fb  = (const float*)d_in[38];

  // workspace layout (floats), ~11.8M floats = 47.3 MB
  float* ws      = (float*)d_ws;
  float* flat    = ws;                       // [4][5376][256] = 5,505,024
  float* mlatb   = ws + 5505024;             // [4][256][4096] = 4,194,304
  float* partial = ws + 9699328;             // [4][8][8][4096] = 1,048,576
  float* mheadb  = ws + 10747904;            // [4][8][4096] = 131,072
  float* h2      = ws + 10878976;            // [800][256] = 204,800
  float* logits  = ws + 11083776;            // [4][5376] = 21,504
  int*   topi    = (int*)(ws + 11105280);    // [400]
  float* gfeat   = ws + 11105680;            // [400][256] = 102,400
  float* dynb    = ws + 11208080;            // [400][169] = 67,600
  float* wt3     = ws + 11275680;            // [256][256] = 65,536
  float* wt4     = ws + 11341216;            // [512][256] = 131,072
  float* wt5     = ws + 11472288;            // [1024][256] = 262,144
  float* wtm     = ws + 11734432;            // [256][256] = 65,536
  float* dout    = (float*)d_out;

  wtrans<<<128, 256, 0, stream>>>(lat3_w, lat4_w, lat5_w, mlat_w, wt3, wt4, wt5, wtm);
  lateral_main<<<1184, 256, 0, stream>>>(x3, x4, x5,
      wt3, lat3_s, lat3_b, wt4, lat4_s, lat4_b, wt5, lat5_s, lat5_b,
      wtm, mlat_s, mlat_b, flat, mlatb);
  conv3<<<512, 256, 0, stream>>>(mlatb, mhead_w, partial);
  mhead_fin<<<512, 256, 0, stream>>>(partial, mhead_s, mhead_b, mheadb);
  loc4<<<768, 256, 0, stream>>>(flat, loc_hw, loc_hb, loc_lng, loc_lnb,
                                loc_fw, loc_fb, logits);
  topk_gather<<<4, 256, 0, stream>>>(logits, flat, topi, gfeat, dout);
  clsker4<<<100, 256, 0, stream>>>(gfeat, h2,
      cls_hw, cls_hb, cls_lng, cls_lnb, ker_hw, ker_hb, ker_lng, ker_lnb);
  heads<<<800, 256, 0, stream>>>(h2, cls_fw, cls_fb, ker_fw, ker_fb, dout, dynb);
  mask_fused<<<1600, 256, 0, stream>>>(dynb, topi, mheadb, dout);
}